// Round 2
// baseline (702.274 us; speedup 1.0000x reference)
//
#include <hip/hip_runtime.h>

#define BATCH 65536

typedef float f32x4 __attribute__((ext_vector_type(4)));
typedef _Float16 f16x8 __attribute__((ext_vector_type(8)));

__device__ __forceinline__ float act_f(float x, float a0, float a1, float a2,
                                       float a3, float a4) {
  float ax = fabsf(x);
  float e = __builtin_amdgcn_exp2f(ax * -2.8853900817779268f);
  float th = (1.0f - e) * __builtin_amdgcn_rcpf(1.0f + e);
  th = copysignf(th, x);
  float arg = fmaf(a1, x, a2);
  float rev = arg * 0.15915494309189535f;
  rev -= floorf(rev);
  float s = __builtin_amdgcn_sinf(rev);
  return fmaf(a3, x, fmaf(a0 * th, s, a4));
}

// split + transpose weights: W[K][N] fp32 -> Wt_hi/lo[N][K] fp16
__global__ __launch_bounds__(256) void splitT_k(const float* __restrict__ W,
                                                _Float16* __restrict__ hi,
                                                _Float16* __restrict__ lo,
                                                int K, int N) {
  const int i = blockIdx.x * 256 + threadIdx.x;
  if (i >= K * N) return;
  const int k = i / N, n = i % N;
  const float w = W[i];
  const _Float16 h = (_Float16)w;
  hi[(size_t)n * K + k] = h;
  lo[(size_t)n * K + k] = (_Float16)(w - (float)h);
}

__device__ __forceinline__ f32x4 mfma3(f16x8 ah, f16x8 al, f16x8 bh, f16x8 bl,
                                       f32x4 c) {
  c = __builtin_amdgcn_mfma_f32_16x16x32_f16(ah, bh, c, 0, 0, 0);
  c = __builtin_amdgcn_mfma_f32_16x16x32_f16(ah, bl, c, 0, 0, 0);
  c = __builtin_amdgcn_mfma_f32_16x16x32_f16(al, bh, c, 0, 0, 0);
  return c;
}

// Fully fused 3-layer MLP + softmax. One block = 64 batch rows, 512 threads.
// Phase 1 (GEMM1): 8 waves as 1m x 8n (no B dup), h1 hi/lo -> LDS (128 KB,
// XOR-swizzled). Phases 2/3: 8 waves as 2m x 4n (A-read dup 4x instead of
// 8x -> phase-2 LDS instrs halved), explicit 2-deep B / 1-deep A register
// prefetch pipeline, setprio around MFMA clusters. h2 computed in 128-col
// panels (32 KB LDS), each consumed immediately by a partial GEMM3.
// Numerics identical to the previous version (same 3-product hi/lo fp16
// compensation, same accumulation order).
__global__ __launch_bounds__(512, 2) void fused_mlp(
    const float* __restrict__ data, const _Float16* __restrict__ w1h,
    const _Float16* __restrict__ w1l, const _Float16* __restrict__ w2h,
    const _Float16* __restrict__ w2l, const _Float16* __restrict__ w3h,
    const _Float16* __restrict__ w3l, const float* __restrict__ b1,
    const float* __restrict__ p1, const float* __restrict__ b2,
    const float* __restrict__ p2, const float* __restrict__ b3,
    const float* __restrict__ p3, float* __restrict__ out) {
  __shared__ __align__(16) char smem[163840];
  char* const h2hB = smem + 131072;  // [64][128] fp16 hi (swizzled)
  char* const h2lB = smem + 147456;  // [64][128] fp16 lo (swizzled)

  const int tid = threadIdx.x;
  const int wv = tid >> 6;
  const int lane = tid & 63;
  const int m16 = lane & 15;
  const int quad = lane >> 4;
  const int kq = quad * 8;
  const int row0 = blockIdx.x * 64;
  const int wm = wv >> 2, wn = wv & 3;  // phases 2/3: 2m x 4n

  const f32x4 zero = {0.f, 0.f, 0.f, 0.f};

  // ---------------- Phase 1: h1 = act(data @ W1 + b1) -> LDS ----------------
  {
    f32x4 acc[4][4];
#pragma unroll
    for (int i = 0; i < 4; ++i)
#pragma unroll
      for (int j = 0; j < 4; ++j) acc[i][j] = zero;

#pragma unroll
    for (int kt = 0; kt < 8; ++kt) {
      const int k = kt * 32 + kq;
      f16x8 ah[4], al[4];
#pragma unroll
      for (int tm = 0; tm < 4; ++tm) {
        const float* pa = data + (size_t)(row0 + tm * 16 + m16) * 256 + k;
        const f32x4 x0 = *(const f32x4*)pa;
        const f32x4 x1 = *(const f32x4*)(pa + 4);
#pragma unroll
        for (int j = 0; j < 4; ++j) {
          const _Float16 g0 = (_Float16)x0[j];
          ah[tm][j] = g0;
          al[tm][j] = (_Float16)(x0[j] - (float)g0);
          const _Float16 g1 = (_Float16)x1[j];
          ah[tm][4 + j] = g1;
          al[tm][4 + j] = (_Float16)(x1[j] - (float)g1);
        }
      }
#pragma unroll
      for (int tn = 0; tn < 4; ++tn) {
        const int col = wv * 64 + tn * 16 + m16;
        const f16x8 bh = *(const f16x8*)(w1h + col * 256 + k);
        const f16x8 bl = *(const f16x8*)(w1l + col * 256 + k);
#pragma unroll
        for (int tm = 0; tm < 4; ++tm)
          acc[tm][tn] = mfma3(ah[tm], al[tm], bh, bl, acc[tm][tn]);
      }
    }
    // epilogue: bias+act, split to fp16 hi/lo, swizzled LDS write
#pragma unroll
    for (int tn = 0; tn < 4; ++tn) {
      const int col = wv * 64 + tn * 16 + m16;
      const float bs = b1[col];
      const float q0 = p1[col * 5 + 0], q1 = p1[col * 5 + 1],
                  q2 = p1[col * 5 + 2], q3 = p1[col * 5 + 3],
                  q4 = p1[col * 5 + 4];
#pragma unroll
      for (int tm = 0; tm < 4; ++tm) {
#pragma unroll
        for (int r = 0; r < 4; ++r) {
          const int row = tm * 16 + quad * 4 + r;
          const float y = act_f(acc[tm][tn][r] + bs, q0, q1, q2, q3, q4);
          const _Float16 h = (_Float16)y;
          const _Float16 l = (_Float16)(y - (float)h);
          const int off = ((row << 10) + (col << 1)) ^ ((row & 7) << 4);
          *(_Float16*)(smem + off) = h;
          *(_Float16*)(smem + 65536 + off) = l;
        }
      }
    }
  }
  __syncthreads();

  // ------- Phase 2+3: per 128-col panel: h2p = act(h1@W2), acc3 += h2p@W3 ---
  f32x4 acc3[2][4];
#pragma unroll
  for (int i = 0; i < 2; ++i)
#pragma unroll
    for (int j = 0; j < 4; ++j) acc3[i][j] = zero;

#pragma unroll 1
  for (int p = 0; p < 4; ++p) {
    // ================= GEMM2 panel (pipelined) =================
    f32x4 acc2[2][2];
#pragma unroll
    for (int i = 0; i < 2; ++i)
#pragma unroll
      for (int j = 0; j < 2; ++j) acc2[i][j] = zero;

    f16x8 Ah[2][2], Al[2][2];  // [buf][tm]
    f16x8 Bh[3][2], Bl[3][2];  // [buf][tn]

    const size_t bbase = (size_t)(p * 128 + wn * 32 + m16) * 512 + kq;

#define LD_A2(buf, kt)                                                        \
  {                                                                           \
    _Pragma("unroll") for (int tm = 0; tm < 2; ++tm) {                        \
      const int row = wm * 32 + tm * 16 + m16;                                \
      const int off =                                                         \
          (((row) << 10) + (((kt)*32 + kq) << 1)) ^ ((m16 & 7) << 4);         \
      Ah[buf][tm] = *(const f16x8*)(smem + off);                              \
      Al[buf][tm] = *(const f16x8*)(smem + 65536 + off);                      \
    }                                                                         \
  }
#define LD_B2(buf, kt)                                                        \
  {                                                                           \
    _Pragma("unroll") for (int tn = 0; tn < 2; ++tn) {                        \
      const size_t o = bbase + (size_t)tn * 16 * 512 + (kt)*32;               \
      Bh[buf][tn] = *(const f16x8*)(w2h + o);                                 \
      Bl[buf][tn] = *(const f16x8*)(w2l + o);                                 \
    }                                                                         \
  }

    LD_B2(0, 0);
    LD_B2(1, 1);
    LD_A2(0, 0);
#pragma unroll
    for (int kt = 0; kt < 16; ++kt) {
      if (kt + 2 < 16) LD_B2((kt + 2) % 3, kt + 2);
      if (kt + 1 < 16) LD_A2((kt + 1) & 1, kt + 1);
      __builtin_amdgcn_s_setprio(1);
#pragma unroll
      for (int tn = 0; tn < 2; ++tn)
#pragma unroll
        for (int tm = 0; tm < 2; ++tm)
          acc2[tm][tn] = mfma3(Ah[kt & 1][tm], Al[kt & 1][tm], Bh[kt % 3][tn],
                               Bl[kt % 3][tn], acc2[tm][tn]);
      __builtin_amdgcn_s_setprio(0);
    }

    // activation params for this wave's 2 columns (issue before barrier so
    // the L2 latency hides in the barrier wait)
    float bs[2], q0[2], q1[2], q2[2], q3[2], q4[2];
#pragma unroll
    for (int tn = 0; tn < 2; ++tn) {
      const int colg = p * 128 + wn * 32 + tn * 16 + m16;
      bs[tn] = b2[colg];
      q0[tn] = p2[colg * 5 + 0];
      q1[tn] = p2[colg * 5 + 1];
      q2[tn] = p2[colg * 5 + 2];
      q3[tn] = p2[colg * 5 + 3];
      q4[tn] = p2[colg * 5 + 4];
    }
    __syncthreads();  // previous panel's GEMM3 reads of h2 are done
    // ---- epilogue: write h2 panel (swizzled fp16 hi/lo) ----
#pragma unroll
    for (int tn = 0; tn < 2; ++tn) {
      const int cl = wn * 32 + tn * 16 + m16;
#pragma unroll
      for (int tm = 0; tm < 2; ++tm) {
#pragma unroll
        for (int r = 0; r < 4; ++r) {
          const int row = wm * 32 + tm * 16 + quad * 4 + r;
          const float y =
              act_f(acc2[tm][tn][r] + bs[tn], q0[tn], q1[tn], q2[tn], q3[tn],
                    q4[tn]);
          const _Float16 h = (_Float16)y;
          const _Float16 l = (_Float16)(y - (float)h);
          const int off = ((row << 8) + (cl << 1)) ^ ((row & 7) << 4);
          *(_Float16*)(h2hB + off) = h;
          *(_Float16*)(h2lB + off) = l;
        }
      }
    }
    __syncthreads();  // h2 panel ready

    // ================= GEMM3 partial (pipelined) =================
    {
      f16x8 Ch[2][2], Cl[2][2];  // [buf][tm] from h2
      f16x8 Dh[2][4], Dl[2][4];  // [buf][tn] from w3

#define LD_C3(buf, kt)                                                        \
  {                                                                           \
    _Pragma("unroll") for (int tm = 0; tm < 2; ++tm) {                        \
      const int row = wm * 32 + tm * 16 + m16;                                \
      const int off =                                                         \
          (((row) << 8) + (((kt)*32 + kq) << 1)) ^ ((m16 & 7) << 4);          \
      Ch[buf][tm] = *(const f16x8*)(h2hB + off);                              \
      Cl[buf][tm] = *(const f16x8*)(h2lB + off);                              \
    }                                                                         \
  }
#define LD_D3(buf, kt)                                                        \
  {                                                                           \
    _Pragma("unroll") for (int tn = 0; tn < 4; ++tn) {                        \
      const size_t o =                                                        \
          (size_t)(wn * 64 + tn * 16 + m16) * 512 + p * 128 + (kt)*32 + kq;   \
      Dh[buf][tn] = *(const f16x8*)(w3h + o);                                 \
      Dl[buf][tn] = *(const f16x8*)(w3l + o);                                 \
    }                                                                         \
  }

      LD_C3(0, 0);
      LD_D3(0, 0);
#pragma unroll
      for (int kt = 0; kt < 4; ++kt) {
        if (kt + 1 < 4) {
          LD_C3((kt + 1) & 1, kt + 1);
          LD_D3((kt + 1) & 1, kt + 1);
        }
        __builtin_amdgcn_s_setprio(1);
#pragma unroll
        for (int tn = 0; tn < 4; ++tn)
#pragma unroll
          for (int tm = 0; tm < 2; ++tm)
            acc3[tm][tn] = mfma3(Ch[kt & 1][tm], Cl[kt & 1][tm], Dh[kt & 1][tn],
                                 Dl[kt & 1][tn], acc3[tm][tn]);
        __builtin_amdgcn_s_setprio(0);
      }
    }
  }
  __syncthreads();  // last GEMM3 reads done; h2 region reusable as scratch

  // ---------------- fused softmax over 256 cols per row ----------------
  float* const red = (float*)(smem + 131072);     // [4 wn][64 rows]
  float* const rowred = (float*)(smem + 132096);  // [64]

  float y[2][4][4];  // [tm][tn][r]
  {
    float bs3[4], s0[4], s1[4], s2[4], s3[4], s4[4];
#pragma unroll
    for (int tn = 0; tn < 4; ++tn) {
      const int colg = wn * 64 + tn * 16 + m16;
      bs3[tn] = b3[colg];
      s0[tn] = p3[colg * 5 + 0];
      s1[tn] = p3[colg * 5 + 1];
      s2[tn] = p3[colg * 5 + 2];
      s3[tn] = p3[colg * 5 + 3];
      s4[tn] = p3[colg * 5 + 4];
    }
#pragma unroll
    for (int tn = 0; tn < 4; ++tn)
#pragma unroll
      for (int tm = 0; tm < 2; ++tm)
#pragma unroll
        for (int r = 0; r < 4; ++r)
          y[tm][tn][r] = act_f(acc3[tm][tn][r] + bs3[tn], s0[tn], s1[tn],
                               s2[tn], s3[tn], s4[tn]);
  }
  // per-(tm,r): max over 4 tn, then 16-lane (m16) butterfly
#pragma unroll
  for (int tm = 0; tm < 2; ++tm)
#pragma unroll
    for (int r = 0; r < 4; ++r) {
      float m = fmaxf(fmaxf(y[tm][0][r], y[tm][1][r]),
                      fmaxf(y[tm][2][r], y[tm][3][r]));
#pragma unroll
      for (int off = 1; off < 16; off <<= 1) m = fmaxf(m, __shfl_xor(m, off));
      if (m16 == 0) {
        const int rowl = wm * 32 + tm * 16 + quad * 4 + r;
        red[wn * 64 + rowl] = m;
      }
    }
  __syncthreads();
  if (tid < 64) {
    const float m = fmaxf(fmaxf(red[tid], red[64 + tid]),
                          fmaxf(red[128 + tid], red[192 + tid]));
    rowred[tid] = m;
  }
  __syncthreads();
#pragma unroll
  for (int tm = 0; tm < 2; ++tm)
#pragma unroll
    for (int r = 0; r < 4; ++r) {
      const int rowl = wm * 32 + tm * 16 + quad * 4 + r;
      const float m = rowred[rowl];
      float s = 0.f;
#pragma unroll
      for (int tn = 0; tn < 4; ++tn) {
        const float e =
            __builtin_amdgcn_exp2f((y[tm][tn][r] - m) * 1.4426950408889634f);
        y[tm][tn][r] = e;
        s += e;
      }
#pragma unroll
      for (int off = 1; off < 16; off <<= 1) s += __shfl_xor(s, off);
      if (m16 == 0) red[wn * 64 + rowl] = s;
    }
  __syncthreads();
  if (tid < 64) {
    const float s = red[tid] + red[64 + tid] + red[128 + tid] + red[192 + tid];
    rowred[tid] = __builtin_amdgcn_rcpf(s);
  }
  __syncthreads();
#pragma unroll
  for (int tm = 0; tm < 2; ++tm)
#pragma unroll
    for (int r = 0; r < 4; ++r) {
      const int rowl = wm * 32 + tm * 16 + quad * 4 + r;
      const float inv = rowred[rowl];
#pragma unroll
      for (int tn = 0; tn < 4; ++tn) {
        const int colg = wn * 64 + tn * 16 + m16;
        out[(size_t)(row0 + rowl) * 256 + colg] = y[tm][tn][r] * inv;
      }
    }
}

extern "C" void kernel_launch(void* const* d_in, const int* in_sizes, int n_in,
                              void* d_out, int out_size, void* d_ws,
                              size_t ws_size, hipStream_t stream) {
  const float* data = (const float*)d_in[0];
  const float* W1 = (const float*)d_in[1];
  const float* b1 = (const float*)d_in[2];
  const float* a1 = (const float*)d_in[3];
  const float* W2 = (const float*)d_in[4];
  const float* b2 = (const float*)d_in[5];
  const float* a2 = (const float*)d_in[6];
  const float* W3 = (const float*)d_in[7];
  const float* b3 = (const float*)d_in[8];
  const float* a3 = (const float*)d_in[9];

  char* ws = (char*)d_ws;
  const size_t KB = 1024;
  _Float16* w1h = (_Float16*)(ws + 0 * KB);    // [512][256]
  _Float16* w1l = (_Float16*)(ws + 256 * KB);
  _Float16* w2h = (_Float16*)(ws + 512 * KB);  // [512][512]
  _Float16* w2l = (_Float16*)(ws + 1024 * KB);
  _Float16* w3h = (_Float16*)(ws + 1536 * KB);  // [256][512]
  _Float16* w3l = (_Float16*)(ws + 1792 * KB);

  splitT_k<<<(256 * 512 + 255) / 256, 256, 0, stream>>>(W1, w1h, w1l, 256, 512);
  splitT_k<<<(512 * 512 + 255) / 256, 256, 0, stream>>>(W2, w2h, w2l, 512, 512);
  splitT_k<<<(512 * 256 + 255) / 256, 256, 0, stream>>>(W3, w3h, w3l, 512, 256);

  fused_mlp<<<BATCH / 64, 512, 0, stream>>>(data, w1h, w1l, w2h, w2l, w3h, w3l,
                                            b1, a1, b2, a2, b3, a3,
                                            (float*)d_out);
}

// Round 3
// 651.088 us; speedup vs baseline: 1.0786x; 1.0786x over previous
//
#include <hip/hip_runtime.h>

#define BATCH 65536

typedef float f32x4 __attribute__((ext_vector_type(4)));
typedef _Float16 f16x8 __attribute__((ext_vector_type(8)));

__device__ __forceinline__ float act_f(float x, float a0, float a1, float a2,
                                       float a3, float a4) {
  float ax = fabsf(x);
  float e = __builtin_amdgcn_exp2f(ax * -2.8853900817779268f);
  float th = (1.0f - e) * __builtin_amdgcn_rcpf(1.0f + e);
  th = copysignf(th, x);
  float arg = fmaf(a1, x, a2);
  float rev = arg * 0.15915494309189535f;
  rev -= floorf(rev);
  float s = __builtin_amdgcn_sinf(rev);
  return fmaf(a3, x, fmaf(a0 * th, s, a4));
}

// split + transpose weights: W[K][N] fp32 -> Wt_hi/lo[N][K] fp16
__global__ __launch_bounds__(256) void splitT_k(const float* __restrict__ W,
                                                _Float16* __restrict__ hi,
                                                _Float16* __restrict__ lo,
                                                int K, int N) {
  const int i = blockIdx.x * 256 + threadIdx.x;
  if (i >= K * N) return;
  const int k = i / N, n = i % N;
  const float w = W[i];
  const _Float16 h = (_Float16)w;
  hi[(size_t)n * K + k] = h;
  lo[(size_t)n * K + k] = (_Float16)(w - (float)h);
}

__device__ __forceinline__ f32x4 mfma3(f16x8 ah, f16x8 al, f16x8 bh, f16x8 bl,
                                       f32x4 c) {
  c = __builtin_amdgcn_mfma_f32_16x16x32_f16(ah, bh, c, 0, 0, 0);
  c = __builtin_amdgcn_mfma_f32_16x16x32_f16(ah, bl, c, 0, 0, 0);
  c = __builtin_amdgcn_mfma_f32_16x16x32_f16(al, bh, c, 0, 0, 0);
  return c;
}

// Fully fused 3-layer MLP + softmax.
// One block = 32 batch rows, 512 threads (8 waves). LDS = 80 KB ->
// 2 blocks/CU co-resident (16 waves/CU, 4/SIMD) for latency hiding; a
// block's barriers overlap with the other block's compute.
//   h1 hi/lo planes [32][512] fp16 (64 KB, XOR-swizzled)
//   h2 panel hi/lo [32][128] fp16 (16 KB), 4 panels, each consumed
//   immediately by a partial GEMM3 accumulation into registers.
// 3-product fp16 hi/lo compensation everywhere; accumulation order per
// output element identical to the verified multi-kernel pipeline.
__global__ __launch_bounds__(512, 4) void fused_mlp(
    const float* __restrict__ data, const _Float16* __restrict__ w1h,
    const _Float16* __restrict__ w1l, const _Float16* __restrict__ w2h,
    const _Float16* __restrict__ w2l, const _Float16* __restrict__ w3h,
    const _Float16* __restrict__ w3l, const float* __restrict__ b1,
    const float* __restrict__ p1, const float* __restrict__ b2,
    const float* __restrict__ p2, const float* __restrict__ b3,
    const float* __restrict__ p3, float* __restrict__ out) {
  __shared__ __align__(16) char smem[81920];
  char* const h2hB = smem + 65536;  // [32][128] fp16 hi (swizzled)
  char* const h2lB = smem + 73728;  // [32][128] fp16 lo (swizzled)

  const int tid = threadIdx.x;
  const int wv = tid >> 6;
  const int lane = tid & 63;
  const int m16 = lane & 15;
  const int quad = lane >> 4;
  const int kq = quad * 8;
  const int row0 = blockIdx.x * 32;

  const f32x4 zero = {0.f, 0.f, 0.f, 0.f};

  // ---------------- Phase 1: h1 = act(data @ W1 + b1) -> LDS ----------------
  {
    f32x4 acc[2][4];
#pragma unroll
    for (int i = 0; i < 2; ++i)
#pragma unroll
      for (int j = 0; j < 4; ++j) acc[i][j] = zero;

#pragma unroll
    for (int kt = 0; kt < 8; ++kt) {
      const int k = kt * 32 + kq;
      f16x8 ah[2], al[2];
#pragma unroll
      for (int tm = 0; tm < 2; ++tm) {
        const float* pa = data + (size_t)(row0 + tm * 16 + m16) * 256 + k;
        const f32x4 x0 = *(const f32x4*)pa;
        const f32x4 x1 = *(const f32x4*)(pa + 4);
#pragma unroll
        for (int j = 0; j < 4; ++j) {
          const _Float16 g0 = (_Float16)x0[j];
          ah[tm][j] = g0;
          al[tm][j] = (_Float16)(x0[j] - (float)g0);
          const _Float16 g1 = (_Float16)x1[j];
          ah[tm][4 + j] = g1;
          al[tm][4 + j] = (_Float16)(x1[j] - (float)g1);
        }
      }
#pragma unroll
      for (int tn = 0; tn < 4; ++tn) {
        const int col = wv * 64 + tn * 16 + m16;
        const f16x8 bh = *(const f16x8*)(w1h + col * 256 + k);
        const f16x8 bl = *(const f16x8*)(w1l + col * 256 + k);
#pragma unroll
        for (int tm = 0; tm < 2; ++tm)
          acc[tm][tn] = mfma3(ah[tm], al[tm], bh, bl, acc[tm][tn]);
      }
    }
    // epilogue: bias+act, split to fp16 hi/lo, swizzled LDS write
#pragma unroll
    for (int tn = 0; tn < 4; ++tn) {
      const int col = wv * 64 + tn * 16 + m16;
      const float bs = b1[col];
      const float q0 = p1[col * 5 + 0], q1 = p1[col * 5 + 1],
                  q2 = p1[col * 5 + 2], q3 = p1[col * 5 + 3],
                  q4 = p1[col * 5 + 4];
#pragma unroll
      for (int tm = 0; tm < 2; ++tm) {
#pragma unroll
        for (int r = 0; r < 4; ++r) {
          const int row = tm * 16 + quad * 4 + r;
          const float y = act_f(acc[tm][tn][r] + bs, q0, q1, q2, q3, q4);
          const _Float16 h = (_Float16)y;
          const _Float16 l = (_Float16)(y - (float)h);
          const int off = ((row << 10) + (col << 1)) ^ ((row & 7) << 4);
          *(_Float16*)(smem + off) = h;
          *(_Float16*)(smem + 32768 + off) = l;
        }
      }
    }
  }
  __syncthreads();

  // ------- Phase 2+3: per 128-col panel: h2p = act(h1@W2), acc3 += h2p@W3 ---
  f32x4 acc3[2][2];
#pragma unroll
  for (int i = 0; i < 2; ++i)
#pragma unroll
    for (int j = 0; j < 2; ++j) acc3[i][j] = zero;

#pragma unroll 1
  for (int p = 0; p < 4; ++p) {
    f32x4 acc2[2];
    acc2[0] = zero;
    acc2[1] = zero;
    const int colw = p * 128 + wv * 16 + m16;  // this thread's W2 column
#pragma unroll
    for (int kt = 0; kt < 16; ++kt) {
      const int k = kt * 32 + kq;
      const f16x8 bh = *(const f16x8*)(w2h + (size_t)colw * 512 + k);
      const f16x8 bl = *(const f16x8*)(w2l + (size_t)colw * 512 + k);
#pragma unroll
      for (int tm = 0; tm < 2; ++tm) {
        const int row = tm * 16 + m16;
        const int off = ((row << 10) + (k << 1)) ^ ((row & 7) << 4);
        const f16x8 ah = *(const f16x8*)(smem + off);
        const f16x8 al = *(const f16x8*)(smem + 32768 + off);
        acc2[tm] = mfma3(ah, al, bh, bl, acc2[tm]);
      }
    }
    // activation params (issue before barrier; L2 latency hides in the wait)
    const float bs = b2[colw];
    const float q0 = p2[colw * 5 + 0], q1 = p2[colw * 5 + 1],
                q2 = p2[colw * 5 + 2], q3 = p2[colw * 5 + 3],
                q4 = p2[colw * 5 + 4];
    __syncthreads();  // previous panel's GEMM3 reads of h2 are done
    // ---- epilogue: write h2 panel (swizzled fp16 hi/lo) ----
    {
      const int cl = wv * 16 + m16;
#pragma unroll
      for (int tm = 0; tm < 2; ++tm) {
#pragma unroll
        for (int r = 0; r < 4; ++r) {
          const int row = tm * 16 + quad * 4 + r;
          const float y = act_f(acc2[tm][r] + bs, q0, q1, q2, q3, q4);
          const _Float16 h = (_Float16)y;
          const _Float16 l = (_Float16)(y - (float)h);
          const int off = ((row << 8) + (cl << 1)) ^ ((row & 7) << 4);
          *(_Float16*)(h2hB + off) = h;
          *(_Float16*)(h2lB + off) = l;
        }
      }
    }
    __syncthreads();  // h2 panel ready
    // GEMM3 partial accumulation, K slice [p*128, p*128+128)
#pragma unroll
    for (int kt = 0; kt < 4; ++kt) {
      const int kl = kt * 32 + kq;
      f16x8 ch[2], co[2];
#pragma unroll
      for (int tm = 0; tm < 2; ++tm) {
        const int row = tm * 16 + m16;
        const int off = ((row << 8) + (kl << 1)) ^ ((row & 7) << 4);
        ch[tm] = *(const f16x8*)(h2hB + off);
        co[tm] = *(const f16x8*)(h2lB + off);
      }
#pragma unroll
      for (int tn = 0; tn < 2; ++tn) {
        const int col = wv * 32 + tn * 16 + m16;
        const f16x8 dh =
            *(const f16x8*)(w3h + (size_t)col * 512 + p * 128 + kl);
        const f16x8 dl =
            *(const f16x8*)(w3l + (size_t)col * 512 + p * 128 + kl);
#pragma unroll
        for (int tm = 0; tm < 2; ++tm)
          acc3[tm][tn] = mfma3(ch[tm], co[tm], dh, dl, acc3[tm][tn]);
      }
    }
  }
  __syncthreads();  // last GEMM3 reads done; h2 region reusable as scratch

  // ---------------- fused softmax over 256 cols per row ----------------
  float* const red = (float*)(smem + 65536);     // [8 wv][32 rows]
  float* const rowred = (float*)(smem + 66560);  // [32]

  float y[2][2][4];  // [tm][tn][r]
  {
    float bs3[2], s0[2], s1[2], s2[2], s3[2], s4[2];
#pragma unroll
    for (int tn = 0; tn < 2; ++tn) {
      const int colg = wv * 32 + tn * 16 + m16;
      bs3[tn] = b3[colg];
      s0[tn] = p3[colg * 5 + 0];
      s1[tn] = p3[colg * 5 + 1];
      s2[tn] = p3[colg * 5 + 2];
      s3[tn] = p3[colg * 5 + 3];
      s4[tn] = p3[colg * 5 + 4];
    }
#pragma unroll
    for (int tn = 0; tn < 2; ++tn)
#pragma unroll
      for (int tm = 0; tm < 2; ++tm)
#pragma unroll
        for (int r = 0; r < 4; ++r)
          y[tm][tn][r] = act_f(acc3[tm][tn][r] + bs3[tn], s0[tn], s1[tn],
                               s2[tn], s3[tn], s4[tn]);
  }
  // per-(tm,r): max over 2 tn, then 16-lane (m16) butterfly
#pragma unroll
  for (int tm = 0; tm < 2; ++tm)
#pragma unroll
    for (int r = 0; r < 4; ++r) {
      float m = fmaxf(y[tm][0][r], y[tm][1][r]);
#pragma unroll
      for (int off = 1; off < 16; off <<= 1) m = fmaxf(m, __shfl_xor(m, off));
      if (m16 == 0) {
        const int rowl = tm * 16 + quad * 4 + r;
        red[wv * 32 + rowl] = m;
      }
    }
  __syncthreads();
  if (tid < 32) {
    float m = red[tid];
#pragma unroll
    for (int w = 1; w < 8; ++w) m = fmaxf(m, red[w * 32 + tid]);
    rowred[tid] = m;
  }
  __syncthreads();
#pragma unroll
  for (int tm = 0; tm < 2; ++tm)
#pragma unroll
    for (int r = 0; r < 4; ++r) {
      const int rowl = tm * 16 + quad * 4 + r;
      const float m = rowred[rowl];
      float s = 0.f;
#pragma unroll
      for (int tn = 0; tn < 2; ++tn) {
        const float e =
            __builtin_amdgcn_exp2f((y[tm][tn][r] - m) * 1.4426950408889634f);
        y[tm][tn][r] = e;
        s += e;
      }
#pragma unroll
      for (int off = 1; off < 16; off <<= 1) s += __shfl_xor(s, off);
      if (m16 == 0) red[wv * 32 + rowl] = s;
    }
  __syncthreads();
  if (tid < 32) {
    float s = red[tid];
#pragma unroll
    for (int w = 1; w < 8; ++w) s += red[w * 32 + tid];
    rowred[tid] = __builtin_amdgcn_rcpf(s);
  }
  __syncthreads();
#pragma unroll
  for (int tm = 0; tm < 2; ++tm)
#pragma unroll
    for (int r = 0; r < 4; ++r) {
      const int rowl = tm * 16 + quad * 4 + r;
      const float inv = rowred[rowl];
#pragma unroll
      for (int tn = 0; tn < 2; ++tn) {
        const int colg = wv * 32 + tn * 16 + m16;
        out[(size_t)(row0 + rowl) * 256 + colg] = y[tm][tn][r] * inv;
      }
    }
}

extern "C" void kernel_launch(void* const* d_in, const int* in_sizes, int n_in,
                              void* d_out, int out_size, void* d_ws,
                              size_t ws_size, hipStream_t stream) {
  const float* data = (const float*)d_in[0];
  const float* W1 = (const float*)d_in[1];
  const float* b1 = (const float*)d_in[2];
  const float* a1 = (const float*)d_in[3];
  const float* W2 = (const float*)d_in[4];
  const float* b2 = (const float*)d_in[5];
  const float* a2 = (const float*)d_in[6];
  const float* W3 = (const float*)d_in[7];
  const float* b3 = (const float*)d_in[8];
  const float* a3 = (const float*)d_in[9];

  char* ws = (char*)d_ws;
  const size_t KB = 1024;
  _Float16* w1h = (_Float16*)(ws + 0 * KB);    // [512][256]
  _Float16* w1l = (_Float16*)(ws + 256 * KB);
  _Float16* w2h = (_Float16*)(ws + 512 * KB);  // [512][512]
  _Float16* w2l = (_Float16*)(ws + 1024 * KB);
  _Float16* w3h = (_Float16*)(ws + 1536 * KB);  // [256][512]
  _Float16* w3l = (_Float16*)(ws + 1792 * KB);

  splitT_k<<<(256 * 512 + 255) / 256, 256, 0, stream>>>(W1, w1h, w1l, 256, 512);
  splitT_k<<<(512 * 512 + 255) / 256, 256, 0, stream>>>(W2, w2h, w2l, 512, 512);
  splitT_k<<<(512 * 256 + 255) / 256, 256, 0, stream>>>(W3, w3h, w3l, 512, 256);

  fused_mlp<<<BATCH / 32, 512, 0, stream>>>(data, w1h, w1l, w2h, w2l, w3h, w3l,
                                            b1, a1, b2, a2, b3, a3,
                                            (float*)d_out);
}

// Round 4
// 548.361 us; speedup vs baseline: 1.2807x; 1.1873x over previous
//
#include <hip/hip_runtime.h>

#define BATCH 65536

typedef float f32x4 __attribute__((ext_vector_type(4)));
typedef _Float16 f16x8 __attribute__((ext_vector_type(8)));

__device__ __forceinline__ float act_f(float x, float a0, float a1, float a2,
                                       float a3, float a4) {
  float ax = fabsf(x);
  float e = __builtin_amdgcn_exp2f(ax * -2.8853900817779268f);
  float th = (1.0f - e) * __builtin_amdgcn_rcpf(1.0f + e);
  th = copysignf(th, x);
  float arg = fmaf(a1, x, a2);
  float rev = arg * 0.15915494309189535f;
  rev -= floorf(rev);
  float s = __builtin_amdgcn_sinf(rev);
  return fmaf(a3, x, fmaf(a0 * th, s, a4));
}

// split + transpose weights: W[K][N] fp32 -> Wt_hi/lo[N][K] fp16
__global__ __launch_bounds__(256) void splitT_k(const float* __restrict__ W,
                                                _Float16* __restrict__ hi,
                                                _Float16* __restrict__ lo,
                                                int K, int N) {
  const int i = blockIdx.x * 256 + threadIdx.x;
  if (i >= K * N) return;
  const int k = i / N, n = i % N;
  const float w = W[i];
  const _Float16 h = (_Float16)w;
  hi[(size_t)n * K + k] = h;
  lo[(size_t)n * K + k] = (_Float16)(w - (float)h);
}

__device__ __forceinline__ f32x4 mfma3(f16x8 ah, f16x8 al, f16x8 bh, f16x8 bl,
                                       f32x4 c) {
  c = __builtin_amdgcn_mfma_f32_16x16x32_f16(ah, bh, c, 0, 0, 0);
  c = __builtin_amdgcn_mfma_f32_16x16x32_f16(ah, bl, c, 0, 0, 0);
  c = __builtin_amdgcn_mfma_f32_16x16x32_f16(al, bh, c, 0, 0, 0);
  return c;
}

// Fully fused 3-layer MLP + softmax. One block = 64 batch rows, 512 threads
// (8 waves), 1 block/CU (latency proven non-bottleneck in r3).
// Phase 1 (1m x 8n): h1 = act(data@W1+b1) -> LDS region A (128 KB, hi/lo
//   fp16 planes, XOR-swizzled byte ^= (row&7)<<4).
// Phase 2 (kt-OUTER, panels-inner): each A fragment read from LDS ONCE per
//   kt and applied to all 4 128-col panels (acc2[4][4] = 64 VGPR) -> A-read
//   volume / 4 vs panel-outer. All of h2 produced at once; h1 is then dead,
//   so h2 overwrites region A (same swizzled layout).
// Phase 3 (2m x 4n): single K=512 pass, A = h2 from region A, B = w3 (L2).
// Softmax fused in-block. 3-product fp16 hi/lo compensation everywhere;
// per-element MFMA sequence and k-order identical to the verified pipeline.
__global__ __launch_bounds__(512, 2) void fused_mlp(
    const float* __restrict__ data, const _Float16* __restrict__ w1h,
    const _Float16* __restrict__ w1l, const _Float16* __restrict__ w2h,
    const _Float16* __restrict__ w2l, const _Float16* __restrict__ w3h,
    const _Float16* __restrict__ w3l, const float* __restrict__ b1,
    const float* __restrict__ p1, const float* __restrict__ b2,
    const float* __restrict__ p2, const float* __restrict__ b3,
    const float* __restrict__ p3, float* __restrict__ out) {
  // region A: [0,65536) hi plane, [65536,131072) lo plane (h1 then h2)
  // scratch:  [131072,132096) red[4][64], [132096,132352) rowred[64]
  __shared__ __align__(16) char smem[132352];
  float* const red = (float*)(smem + 131072);
  float* const rowred = (float*)(smem + 132096);

  const int tid = threadIdx.x;
  const int wv = tid >> 6;
  const int lane = tid & 63;
  const int m16 = lane & 15;
  const int quad = lane >> 4;
  const int kq = quad * 8;
  const int row0 = blockIdx.x * 64;

  const f32x4 zero = {0.f, 0.f, 0.f, 0.f};

  // ---------------- Phase 1: h1 = act(data @ W1 + b1) -> LDS ----------------
  {
    f32x4 acc[4][4];
#pragma unroll
    for (int i = 0; i < 4; ++i)
#pragma unroll
      for (int j = 0; j < 4; ++j) acc[i][j] = zero;

#pragma unroll
    for (int kt = 0; kt < 8; ++kt) {
      const int k = kt * 32 + kq;
      f16x8 ah[4], al[4];
#pragma unroll
      for (int tm = 0; tm < 4; ++tm) {
        const float* pa = data + (size_t)(row0 + tm * 16 + m16) * 256 + k;
        const f32x4 x0 = *(const f32x4*)pa;
        const f32x4 x1 = *(const f32x4*)(pa + 4);
#pragma unroll
        for (int j = 0; j < 4; ++j) {
          const _Float16 g0 = (_Float16)x0[j];
          ah[tm][j] = g0;
          al[tm][j] = (_Float16)(x0[j] - (float)g0);
          const _Float16 g1 = (_Float16)x1[j];
          ah[tm][4 + j] = g1;
          al[tm][4 + j] = (_Float16)(x1[j] - (float)g1);
        }
      }
#pragma unroll
      for (int tn = 0; tn < 4; ++tn) {
        const int col = wv * 64 + tn * 16 + m16;
        const f16x8 bh = *(const f16x8*)(w1h + col * 256 + k);
        const f16x8 bl = *(const f16x8*)(w1l + col * 256 + k);
#pragma unroll
        for (int tm = 0; tm < 4; ++tm)
          acc[tm][tn] = mfma3(ah[tm], al[tm], bh, bl, acc[tm][tn]);
      }
    }
    // epilogue: bias+act, split to fp16 hi/lo, swizzled LDS write
#pragma unroll
    for (int tn = 0; tn < 4; ++tn) {
      const int col = wv * 64 + tn * 16 + m16;
      const float bs = b1[col];
      const float q0 = p1[col * 5 + 0], q1 = p1[col * 5 + 1],
                  q2 = p1[col * 5 + 2], q3 = p1[col * 5 + 3],
                  q4 = p1[col * 5 + 4];
#pragma unroll
      for (int tm = 0; tm < 4; ++tm) {
#pragma unroll
        for (int r = 0; r < 4; ++r) {
          const int row = tm * 16 + quad * 4 + r;
          const float y = act_f(acc[tm][tn][r] + bs, q0, q1, q2, q3, q4);
          const _Float16 h = (_Float16)y;
          const _Float16 l = (_Float16)(y - (float)h);
          const int off = ((row << 10) + (col << 1)) ^ ((row & 7) << 4);
          *(_Float16*)(smem + off) = h;
          *(_Float16*)(smem + 65536 + off) = l;
        }
      }
    }
  }
  __syncthreads();

  // ------ Phase 2: h2 = act(h1 @ W2 + b2), kt-outer over all 4 panels ------
  f32x4 acc2[4][4];  // [panel][tm]
#pragma unroll
  for (int i = 0; i < 4; ++i)
#pragma unroll
    for (int j = 0; j < 4; ++j) acc2[i][j] = zero;

  const int c2 = wv * 16 + m16;  // within-panel column owned by this thread

#pragma unroll 2
  for (int kt = 0; kt < 16; ++kt) {
    const int k = kt * 32 + kq;
    f16x8 ah[4], al[4];
#pragma unroll
    for (int tm = 0; tm < 4; ++tm) {
      // row = tm*16+m16 -> row&7 == m16&7
      const int off = (((tm * 16 + m16) << 10) + (k << 1)) ^ ((m16 & 7) << 4);
      ah[tm] = *(const f16x8*)(smem + off);
      al[tm] = *(const f16x8*)(smem + 65536 + off);
    }
#pragma unroll
    for (int p = 0; p < 4; ++p) {
      const size_t o = (size_t)(p * 128 + c2) * 512 + k;
      const f16x8 bh = *(const f16x8*)(w2h + o);
      const f16x8 bl = *(const f16x8*)(w2l + o);
#pragma unroll
      for (int tm = 0; tm < 4; ++tm)
        acc2[p][tm] = mfma3(ah[tm], al[tm], bh, bl, acc2[p][tm]);
    }
  }

  // activation params (issue before barrier; L2 latency hides in the wait)
  float bs2[4], q0[4], q1[4], q2[4], q3[4], q4[4];
#pragma unroll
  for (int p = 0; p < 4; ++p) {
    const int colg = p * 128 + c2;
    bs2[p] = b2[colg];
    q0[p] = p2[colg * 5 + 0];
    q1[p] = p2[colg * 5 + 1];
    q2[p] = p2[colg * 5 + 2];
    q3[p] = p2[colg * 5 + 3];
    q4[p] = p2[colg * 5 + 4];
  }
  __syncthreads();  // all reads of h1 complete; region A reusable

  // epilogue: write full h2 (hi/lo, swizzled) over region A
#pragma unroll
  for (int p = 0; p < 4; ++p) {
    const int col = p * 128 + c2;
#pragma unroll
    for (int tm = 0; tm < 4; ++tm) {
#pragma unroll
      for (int r = 0; r < 4; ++r) {
        const int row = tm * 16 + quad * 4 + r;
        const float y =
            act_f(acc2[p][tm][r] + bs2[p], q0[p], q1[p], q2[p], q3[p], q4[p]);
        const _Float16 h = (_Float16)y;
        const _Float16 l = (_Float16)(y - (float)h);
        const int off = ((row << 10) + (col << 1)) ^ ((row & 7) << 4);
        *(_Float16*)(smem + off) = h;
        *(_Float16*)(smem + 65536 + off) = l;
      }
    }
  }
  __syncthreads();  // h2 ready

  // ---------- Phase 3: out_pre = act(h2 @ W3 + b3), 2m x 4n, K=512 ---------
  const int wm = wv >> 2, wn = wv & 3;
  f32x4 acc3[2][4];  // [tm][tn]
#pragma unroll
  for (int i = 0; i < 2; ++i)
#pragma unroll
    for (int j = 0; j < 4; ++j) acc3[i][j] = zero;

#pragma unroll 2
  for (int kt = 0; kt < 16; ++kt) {
    const int k = kt * 32 + kq;
    f16x8 ch[2], cl[2];
#pragma unroll
    for (int tm = 0; tm < 2; ++tm) {
      // row = wm*32 + tm*16 + m16 -> row&7 == m16&7
      const int off =
          (((wm * 32 + tm * 16 + m16) << 10) + (k << 1)) ^ ((m16 & 7) << 4);
      ch[tm] = *(const f16x8*)(smem + off);
      cl[tm] = *(const f16x8*)(smem + 65536 + off);
    }
#pragma unroll
    for (int tn = 0; tn < 4; ++tn) {
      const int col = wn * 64 + tn * 16 + m16;
      const size_t o = (size_t)col * 512 + k;
      const f16x8 dh = *(const f16x8*)(w3h + o);
      const f16x8 dl = *(const f16x8*)(w3l + o);
#pragma unroll
      for (int tm = 0; tm < 2; ++tm)
        acc3[tm][tn] = mfma3(ch[tm], cl[tm], dh, dl, acc3[tm][tn]);
    }
  }

  // ---------------- fused softmax over 256 cols per row ----------------
  // wave covers rows [wm*32, wm*32+32) x cols [wn*64, wn*64+64)
  float y[2][4][4];  // [tm][tn][r]
  {
    float bs3[4], s0[4], s1[4], s2[4], s3[4], s4[4];
#pragma unroll
    for (int tn = 0; tn < 4; ++tn) {
      const int colg = wn * 64 + tn * 16 + m16;
      bs3[tn] = b3[colg];
      s0[tn] = p3[colg * 5 + 0];
      s1[tn] = p3[colg * 5 + 1];
      s2[tn] = p3[colg * 5 + 2];
      s3[tn] = p3[colg * 5 + 3];
      s4[tn] = p3[colg * 5 + 4];
    }
#pragma unroll
    for (int tn = 0; tn < 4; ++tn)
#pragma unroll
      for (int tm = 0; tm < 2; ++tm)
#pragma unroll
        for (int r = 0; r < 4; ++r)
          y[tm][tn][r] = act_f(acc3[tm][tn][r] + bs3[tn], s0[tn], s1[tn],
                               s2[tn], s3[tn], s4[tn]);
  }
  // per-(tm,r): max over 4 tn, then 16-lane (m16) butterfly
#pragma unroll
  for (int tm = 0; tm < 2; ++tm)
#pragma unroll
    for (int r = 0; r < 4; ++r) {
      float m = fmaxf(fmaxf(y[tm][0][r], y[tm][1][r]),
                      fmaxf(y[tm][2][r], y[tm][3][r]));
#pragma unroll
      for (int off = 1; off < 16; off <<= 1) m = fmaxf(m, __shfl_xor(m, off));
      if (m16 == 0) {
        const int rowl = wm * 32 + tm * 16 + quad * 4 + r;
        red[wn * 64 + rowl] = m;
      }
    }
  __syncthreads();
  if (tid < 64) {
    rowred[tid] = fmaxf(fmaxf(red[tid], red[64 + tid]),
                        fmaxf(red[128 + tid], red[192 + tid]));
  }
  __syncthreads();
#pragma unroll
  for (int tm = 0; tm < 2; ++tm)
#pragma unroll
    for (int r = 0; r < 4; ++r) {
      const int rowl = wm * 32 + tm * 16 + quad * 4 + r;
      const float m = rowred[rowl];
      float s = 0.f;
#pragma unroll
      for (int tn = 0; tn < 4; ++tn) {
        const float e =
            __builtin_amdgcn_exp2f((y[tm][tn][r] - m) * 1.4426950408889634f);
        y[tm][tn][r] = e;
        s += e;
      }
#pragma unroll
      for (int off = 1; off < 16; off <<= 1) s += __shfl_xor(s, off);
      if (m16 == 0) red[wn * 64 + rowl] = s;
    }
  __syncthreads();
  if (tid < 64) {
    const float s = red[tid] + red[64 + tid] + red[128 + tid] + red[192 + tid];
    rowred[tid] = __builtin_amdgcn_rcpf(s);
  }
  __syncthreads();
#pragma unroll
  for (int tm = 0; tm < 2; ++tm)
#pragma unroll
    for (int r = 0; r < 4; ++r) {
      const int rowl = wm * 32 + tm * 16 + quad * 4 + r;
      const float inv = rowred[rowl];
#pragma unroll
      for (int tn = 0; tn < 4; ++tn) {
        const int colg = wn * 64 + tn * 16 + m16;
        out[(size_t)(row0 + rowl) * 256 + colg] = y[tm][tn][r] * inv;
      }
    }
}

extern "C" void kernel_launch(void* const* d_in, const int* in_sizes, int n_in,
                              void* d_out, int out_size, void* d_ws,
                              size_t ws_size, hipStream_t stream) {
  const float* data = (const float*)d_in[0];
  const float* W1 = (const float*)d_in[1];
  const float* b1 = (const float*)d_in[2];
  const float* a1 = (const float*)d_in[3];
  const float* W2 = (const float*)d_in[4];
  const float* b2 = (const float*)d_in[5];
  const float* a2 = (const float*)d_in[6];
  const float* W3 = (const float*)d_in[7];
  const float* b3 = (const float*)d_in[8];
  const float* a3 = (const float*)d_in[9];

  char* ws = (char*)d_ws;
  const size_t KB = 1024;
  _Float16* w1h = (_Float16*)(ws + 0 * KB);    // [512][256]
  _Float16* w1l = (_Float16*)(ws + 256 * KB);
  _Float16* w2h = (_Float16*)(ws + 512 * KB);  // [512][512]
  _Float16* w2l = (_Float16*)(ws + 1024 * KB);
  _Float16* w3h = (_Float16*)(ws + 1536 * KB);  // [256][512]
  _Float16* w3l = (_Float16*)(ws + 1792 * KB);

  splitT_k<<<(256 * 512 + 255) / 256, 256, 0, stream>>>(W1, w1h, w1l, 256, 512);
  splitT_k<<<(512 * 512 + 255) / 256, 256, 0, stream>>>(W2, w2h, w2l, 512, 512);
  splitT_k<<<(512 * 256 + 255) / 256, 256, 0, stream>>>(W3, w3h, w3l, 512, 256);

  fused_mlp<<<BATCH / 64, 512, 0, stream>>>(data, w1h, w1l, w2h, w2l, w3h, w3l,
                                            b1, a1, b2, a2, b3, a3,
                                            (float*)d_out);
}

// Round 5
// 532.251 us; speedup vs baseline: 1.3194x; 1.0303x over previous
//
#include <hip/hip_runtime.h>

#define BATCH 65536

typedef float f32x4 __attribute__((ext_vector_type(4)));
typedef _Float16 f16x8 __attribute__((ext_vector_type(8)));

__device__ __forceinline__ float act_f(float x, float a0, float a1, float a2,
                                       float a3, float a4) {
  float ax = fabsf(x);
  float e = __builtin_amdgcn_exp2f(ax * -2.8853900817779268f);
  float th = (1.0f - e) * __builtin_amdgcn_rcpf(1.0f + e);
  th = copysignf(th, x);
  float arg = fmaf(a1, x, a2);
  float rev = arg * 0.15915494309189535f;
  rev -= floorf(rev);
  float s = __builtin_amdgcn_sinf(rev);
  return fmaf(a3, x, fmaf(a0 * th, s, a4));
}

// split + transpose weights: W[K][N] fp32 -> Wt_hi/lo[N][K] fp16
__global__ __launch_bounds__(256) void splitT_k(const float* __restrict__ W,
                                                _Float16* __restrict__ hi,
                                                _Float16* __restrict__ lo,
                                                int K, int N) {
  const int i = blockIdx.x * 256 + threadIdx.x;
  if (i >= K * N) return;
  const int k = i / N, n = i % N;
  const float w = W[i];
  const _Float16 h = (_Float16)w;
  hi[(size_t)n * K + k] = h;
  lo[(size_t)n * K + k] = (_Float16)(w - (float)h);
}

__device__ __forceinline__ f32x4 mfma3(f16x8 ah, f16x8 al, f16x8 bh, f16x8 bl,
                                       f32x4 c) {
  c = __builtin_amdgcn_mfma_f32_16x16x32_f16(ah, bh, c, 0, 0, 0);
  c = __builtin_amdgcn_mfma_f32_16x16x32_f16(ah, bl, c, 0, 0, 0);
  c = __builtin_amdgcn_mfma_f32_16x16x32_f16(al, bh, c, 0, 0, 0);
  return c;
}

// Fully fused 3-layer MLP + softmax. One block = 64 batch rows, 512 threads.
// Same structure as r4 (kt-outer phase 2, h2 overwrites h1's LDS region),
// plus explicit 1-kt-deep register double-buffering of all GLOBAL loads
// (weights from L2, P1 data from HBM) with STATIC buffer indices (hand-
// written paired loop bodies, no dynamic register indexing -> no scratch).
// VGPR budget raised toward the 256 cap allowed by __launch_bounds__(512,2).
// Per-element MFMA sequence and k-order identical to r4 (bitwise).
__global__ __launch_bounds__(512, 2) void fused_mlp(
    const float* __restrict__ data, const _Float16* __restrict__ w1h,
    const _Float16* __restrict__ w1l, const _Float16* __restrict__ w2h,
    const _Float16* __restrict__ w2l, const _Float16* __restrict__ w3h,
    const _Float16* __restrict__ w3l, const float* __restrict__ b1,
    const float* __restrict__ p1, const float* __restrict__ b2,
    const float* __restrict__ p2, const float* __restrict__ b3,
    const float* __restrict__ p3, float* __restrict__ out) {
  // region A: [0,65536) hi plane, [65536,131072) lo plane (h1 then h2)
  // scratch:  [131072,132096) red[4][64], [132096,132352) rowred[64]
  __shared__ __align__(16) char smem[132352];
  float* const red = (float*)(smem + 131072);
  float* const rowred = (float*)(smem + 132096);

  const int tid = threadIdx.x;
  const int wv = tid >> 6;
  const int lane = tid & 63;
  const int m16 = lane & 15;
  const int quad = lane >> 4;
  const int kq = quad * 8;
  const int row0 = blockIdx.x * 64;

  const f32x4 zero = {0.f, 0.f, 0.f, 0.f};

  // ---------------- Phase 1: h1 = act(data @ W1 + b1) -> LDS ----------------
  {
    f32x4 acc[4][4];
#pragma unroll
    for (int i = 0; i < 4; ++i)
#pragma unroll
      for (int j = 0; j < 4; ++j) acc[i][j] = zero;

    const float* rp0 = data + (size_t)(row0 + 0 * 16 + m16) * 256 + kq;
    const float* rp1 = data + (size_t)(row0 + 1 * 16 + m16) * 256 + kq;
    const float* rp2 = data + (size_t)(row0 + 2 * 16 + m16) * 256 + kq;
    const float* rp3 = data + (size_t)(row0 + 3 * 16 + m16) * 256 + kq;
    const _Float16* b1hp = w1h + (size_t)(wv * 64 + m16) * 256 + kq;
    const _Float16* b1lp = w1l + (size_t)(wv * 64 + m16) * 256 + kq;

    f32x4 Ax[2][4][2];  // [buf][tm][half] -- buf index ALWAYS literal

#define P1_LDA(buf, kt)                                   \
  {                                                       \
    Ax[buf][0][0] = *(const f32x4*)(rp0 + (kt) * 32);     \
    Ax[buf][0][1] = *(const f32x4*)(rp0 + (kt) * 32 + 4); \
    Ax[buf][1][0] = *(const f32x4*)(rp1 + (kt) * 32);     \
    Ax[buf][1][1] = *(const f32x4*)(rp1 + (kt) * 32 + 4); \
    Ax[buf][2][0] = *(const f32x4*)(rp2 + (kt) * 32);     \
    Ax[buf][2][1] = *(const f32x4*)(rp2 + (kt) * 32 + 4); \
    Ax[buf][3][0] = *(const f32x4*)(rp3 + (kt) * 32);     \
    Ax[buf][3][1] = *(const f32x4*)(rp3 + (kt) * 32 + 4); \
  }

#define P1_WORK(buf, kt)                                                    \
  {                                                                         \
    f16x8 bh_[4], bl_[4];                                                   \
    _Pragma("unroll") for (int tn = 0; tn < 4; ++tn) {                      \
      bh_[tn] = *(const f16x8*)(b1hp + tn * 16 * 256 + (kt) * 32);          \
      bl_[tn] = *(const f16x8*)(b1lp + tn * 16 * 256 + (kt) * 32);          \
    }                                                                       \
    f16x8 ah_[4], al_[4];                                                   \
    _Pragma("unroll") for (int tm = 0; tm < 4; ++tm) {                      \
      _Pragma("unroll") for (int j = 0; j < 4; ++j) {                       \
        const float v0 = Ax[buf][tm][0][j];                                 \
        const _Float16 g0 = (_Float16)v0;                                   \
        ah_[tm][j] = g0;                                                    \
        al_[tm][j] = (_Float16)(v0 - (float)g0);                            \
        const float v1 = Ax[buf][tm][1][j];                                 \
        const _Float16 g1 = (_Float16)v1;                                   \
        ah_[tm][4 + j] = g1;                                                \
        al_[tm][4 + j] = (_Float16)(v1 - (float)g1);                        \
      }                                                                     \
    }                                                                       \
    _Pragma("unroll") for (int tn = 0; tn < 4; ++tn)                        \
        _Pragma("unroll") for (int tm = 0; tm < 4; ++tm) acc[tm][tn] =      \
        mfma3(ah_[tm], al_[tm], bh_[tn], bl_[tn], acc[tm][tn]);             \
  }

    P1_LDA(0, 0);
#pragma unroll 1
    for (int i = 0; i < 4; ++i) {
      P1_LDA(1, 2 * i + 1);
      P1_WORK(0, 2 * i);
      if (i < 3) P1_LDA(0, 2 * i + 2);
      P1_WORK(1, 2 * i + 1);
    }

    // epilogue: bias+act, split to fp16 hi/lo, swizzled LDS write
#pragma unroll
    for (int tn = 0; tn < 4; ++tn) {
      const int col = wv * 64 + tn * 16 + m16;
      const float bs = b1[col];
      const float q0 = p1[col * 5 + 0], q1 = p1[col * 5 + 1],
                  q2 = p1[col * 5 + 2], q3 = p1[col * 5 + 3],
                  q4 = p1[col * 5 + 4];
#pragma unroll
      for (int tm = 0; tm < 4; ++tm) {
#pragma unroll
        for (int r = 0; r < 4; ++r) {
          const int row = tm * 16 + quad * 4 + r;
          const float y = act_f(acc[tm][tn][r] + bs, q0, q1, q2, q3, q4);
          const _Float16 h = (_Float16)y;
          const _Float16 l = (_Float16)(y - (float)h);
          const int off = ((row << 10) + (col << 1)) ^ ((row & 7) << 4);
          *(_Float16*)(smem + off) = h;
          *(_Float16*)(smem + 65536 + off) = l;
        }
      }
    }
  }
  __syncthreads();

  // ------ Phase 2: h2 = act(h1 @ W2 + b2), kt-outer over all 4 panels ------
  f32x4 acc2[4][4];  // [panel][tm]
#pragma unroll
  for (int i = 0; i < 4; ++i)
#pragma unroll
    for (int j = 0; j < 4; ++j) acc2[i][j] = zero;

  const int c2 = wv * 16 + m16;  // within-panel column owned by this thread
  {
    const _Float16* b2hp = w2h + (size_t)c2 * 512 + kq;
    const _Float16* b2lp = w2l + (size_t)c2 * 512 + kq;

    f16x8 Bh[2][4], Bl[2][4];  // [buf][panel] -- buf index ALWAYS literal

#define P2_LDB(buf, kt)                                                  \
  {                                                                      \
    _Pragma("unroll") for (int p = 0; p < 4; ++p) {                      \
      Bh[buf][p] = *(const f16x8*)(b2hp + (size_t)p * 65536 + (kt) * 32);\
      Bl[buf][p] = *(const f16x8*)(b2lp + (size_t)p * 65536 + (kt) * 32);\
    }                                                                    \
  }

#define P2_WORK(buf, kt)                                                   \
  {                                                                        \
    f16x8 ah_[4], al_[4];                                                  \
    _Pragma("unroll") for (int tm = 0; tm < 4; ++tm) {                     \
      const int off = (((tm * 16 + m16) << 10) + (((kt) * 32 + kq) << 1)) ^\
                      ((m16 & 7) << 4);                                    \
      ah_[tm] = *(const f16x8*)(smem + off);                               \
      al_[tm] = *(const f16x8*)(smem + 65536 + off);                       \
    }                                                                      \
    _Pragma("unroll") for (int p = 0; p < 4; ++p)                          \
        _Pragma("unroll") for (int tm = 0; tm < 4; ++tm) acc2[p][tm] =     \
        mfma3(ah_[tm], al_[tm], Bh[buf][p], Bl[buf][p], acc2[p][tm]);      \
  }

    P2_LDB(0, 0);
#pragma unroll 1
    for (int i = 0; i < 8; ++i) {
      P2_LDB(1, 2 * i + 1);
      P2_WORK(0, 2 * i);
      if (i < 7) P2_LDB(0, 2 * i + 2);
      P2_WORK(1, 2 * i + 1);
    }
  }

  // activation params (issue before barrier; L2 latency hides in the wait)
  float bs2[4], q0[4], q1[4], q2[4], q3[4], q4[4];
#pragma unroll
  for (int p = 0; p < 4; ++p) {
    const int colg = p * 128 + c2;
    bs2[p] = b2[colg];
    q0[p] = p2[colg * 5 + 0];
    q1[p] = p2[colg * 5 + 1];
    q2[p] = p2[colg * 5 + 2];
    q3[p] = p2[colg * 5 + 3];
    q4[p] = p2[colg * 5 + 4];
  }
  __syncthreads();  // all reads of h1 complete; region A reusable

  // epilogue: write full h2 (hi/lo, swizzled) over region A
#pragma unroll
  for (int p = 0; p < 4; ++p) {
    const int col = p * 128 + c2;
#pragma unroll
    for (int tm = 0; tm < 4; ++tm) {
#pragma unroll
      for (int r = 0; r < 4; ++r) {
        const int row = tm * 16 + quad * 4 + r;
        const float y =
            act_f(acc2[p][tm][r] + bs2[p], q0[p], q1[p], q2[p], q3[p], q4[p]);
        const _Float16 h = (_Float16)y;
        const _Float16 l = (_Float16)(y - (float)h);
        const int off = ((row << 10) + (col << 1)) ^ ((row & 7) << 4);
        *(_Float16*)(smem + off) = h;
        *(_Float16*)(smem + 65536 + off) = l;
      }
    }
  }
  __syncthreads();  // h2 ready

  // ---------- Phase 3: out_pre = act(h2 @ W3 + b3), 2m x 4n, K=512 ---------
  const int wm = wv >> 2, wn = wv & 3;
  f32x4 acc3[2][4];  // [tm][tn]
#pragma unroll
  for (int i = 0; i < 2; ++i)
#pragma unroll
    for (int j = 0; j < 4; ++j) acc3[i][j] = zero;

  {
    const _Float16* b3hp = w3h + (size_t)(wn * 64 + m16) * 512 + kq;
    const _Float16* b3lp = w3l + (size_t)(wn * 64 + m16) * 512 + kq;

    f16x8 Dh[2][4], Dl[2][4];  // [buf][tn] -- buf index ALWAYS literal

#define P3_LDB(buf, kt)                                                 \
  {                                                                     \
    _Pragma("unroll") for (int tn = 0; tn < 4; ++tn) {                  \
      Dh[buf][tn] = *(const f16x8*)(b3hp + (size_t)tn * 8192 + (kt) * 32);\
      Dl[buf][tn] = *(const f16x8*)(b3lp + (size_t)tn * 8192 + (kt) * 32);\
    }                                                                   \
  }

#define P3_WORK(buf, kt)                                                    \
  {                                                                         \
    f16x8 ch_[2], cl_[2];                                                   \
    _Pragma("unroll") for (int tm = 0; tm < 2; ++tm) {                      \
      const int off = (((wm * 32 + tm * 16 + m16) << 10) +                  \
                       (((kt) * 32 + kq) << 1)) ^                           \
                      ((m16 & 7) << 4);                                     \
      ch_[tm] = *(const f16x8*)(smem + off);                                \
      cl_[tm] = *(const f16x8*)(smem + 65536 + off);                        \
    }                                                                       \
    _Pragma("unroll") for (int tn = 0; tn < 4; ++tn)                        \
        _Pragma("unroll") for (int tm = 0; tm < 2; ++tm) acc3[tm][tn] =     \
        mfma3(ch_[tm], cl_[tm], Dh[buf][tn], Dl[buf][tn], acc3[tm][tn]);    \
  }

    P3_LDB(0, 0);
#pragma unroll 1
    for (int i = 0; i < 8; ++i) {
      P3_LDB(1, 2 * i + 1);
      P3_WORK(0, 2 * i);
      if (i < 7) P3_LDB(0, 2 * i + 2);
      P3_WORK(1, 2 * i + 1);
    }
  }

  // ---------------- fused softmax over 256 cols per row ----------------
  // wave covers rows [wm*32, wm*32+32) x cols [wn*64, wn*64+64)
  float y[2][4][4];  // [tm][tn][r]
  {
    float bs3[4], s0[4], s1[4], s2[4], s3[4], s4[4];
#pragma unroll
    for (int tn = 0; tn < 4; ++tn) {
      const int colg = wn * 64 + tn * 16 + m16;
      bs3[tn] = b3[colg];
      s0[tn] = p3[colg * 5 + 0];
      s1[tn] = p3[colg * 5 + 1];
      s2[tn] = p3[colg * 5 + 2];
      s3[tn] = p3[colg * 5 + 3];
      s4[tn] = p3[colg * 5 + 4];
    }
#pragma unroll
    for (int tn = 0; tn < 4; ++tn)
#pragma unroll
      for (int tm = 0; tm < 2; ++tm)
#pragma unroll
        for (int r = 0; r < 4; ++r)
          y[tm][tn][r] = act_f(acc3[tm][tn][r] + bs3[tn], s0[tn], s1[tn],
                               s2[tn], s3[tn], s4[tn]);
  }
  // per-(tm,r): max over 4 tn, then 16-lane (m16) butterfly
#pragma unroll
  for (int tm = 0; tm < 2; ++tm)
#pragma unroll
    for (int r = 0; r < 4; ++r) {
      float m = fmaxf(fmaxf(y[tm][0][r], y[tm][1][r]),
                      fmaxf(y[tm][2][r], y[tm][3][r]));
#pragma unroll
      for (int off = 1; off < 16; off <<= 1) m = fmaxf(m, __shfl_xor(m, off));
      if (m16 == 0) {
        const int rowl = wm * 32 + tm * 16 + quad * 4 + r;
        red[wn * 64 + rowl] = m;
      }
    }
  __syncthreads();
  if (tid < 64) {
    rowred[tid] = fmaxf(fmaxf(red[tid], red[64 + tid]),
                        fmaxf(red[128 + tid], red[192 + tid]));
  }
  __syncthreads();
#pragma unroll
  for (int tm = 0; tm < 2; ++tm)
#pragma unroll
    for (int r = 0; r < 4; ++r) {
      const int rowl = wm * 32 + tm * 16 + quad * 4 + r;
      const float m = rowred[rowl];
      float s = 0.f;
#pragma unroll
      for (int tn = 0; tn < 4; ++tn) {
        const float e =
            __builtin_amdgcn_exp2f((y[tm][tn][r] - m) * 1.4426950408889634f);
        y[tm][tn][r] = e;
        s += e;
      }
#pragma unroll
      for (int off = 1; off < 16; off <<= 1) s += __shfl_xor(s, off);
      if (m16 == 0) red[wn * 64 + rowl] = s;
    }
  __syncthreads();
  if (tid < 64) {
    const float s = red[tid] + red[64 + tid] + red[128 + tid] + red[192 + tid];
    rowred[tid] = __builtin_amdgcn_rcpf(s);
  }
  __syncthreads();
#pragma unroll
  for (int tm = 0; tm < 2; ++tm)
#pragma unroll
    for (int r = 0; r < 4; ++r) {
      const int rowl = wm * 32 + tm * 16 + quad * 4 + r;
      const float inv = rowred[rowl];
#pragma unroll
      for (int tn = 0; tn < 4; ++tn) {
        const int colg = wn * 64 + tn * 16 + m16;
        out[(size_t)(row0 + rowl) * 256 + colg] = y[tm][tn][r] * inv;
      }
    }
}

extern "C" void kernel_launch(void* const* d_in, const int* in_sizes, int n_in,
                              void* d_out, int out_size, void* d_ws,
                              size_t ws_size, hipStream_t stream) {
  const float* data = (const float*)d_in[0];
  const float* W1 = (const float*)d_in[1];
  const float* b1 = (const float*)d_in[2];
  const float* a1 = (const float*)d_in[3];
  const float* W2 = (const float*)d_in[4];
  const float* b2 = (const float*)d_in[5];
  const float* a2 = (const float*)d_in[6];
  const float* W3 = (const float*)d_in[7];
  const float* b3 = (const float*)d_in[8];
  const float* a3 = (const float*)d_in[9];

  char* ws = (char*)d_ws;
  const size_t KB = 1024;
  _Float16* w1h = (_Float16*)(ws + 0 * KB);    // [512][256]
  _Float16* w1l = (_Float16*)(ws + 256 * KB);
  _Float16* w2h = (_Float16*)(ws + 512 * KB);  // [512][512]
  _Float16* w2l = (_Float16*)(ws + 1024 * KB);
  _Float16* w3h = (_Float16*)(ws + 1536 * KB);  // [256][512]
  _Float16* w3l = (_Float16*)(ws + 1792 * KB);

  splitT_k<<<(256 * 512 + 255) / 256, 256, 0, stream>>>(W1, w1h, w1l, 256, 512);
  splitT_k<<<(512 * 512 + 255) / 256, 256, 0, stream>>>(W2, w2h, w2l, 512, 512);
  splitT_k<<<(512 * 256 + 255) / 256, 256, 0, stream>>>(W3, w3h, w3l, 512, 256);

  fused_mlp<<<BATCH / 64, 512, 0, stream>>>(data, w1h, w1l, w2h, w2l, w3h, w3l,
                                            b1, a1, b2, a2, b3, a3,
                                            (float*)d_out);
}